// Round 3
// baseline (5103.237 us; speedup 1.0000x reference)
//
#include <hip/hip_runtime.h>
#include <math.h>

#define N 96
#define T 768          // 12 waves, one workgroup, one CU
#define ITERS 50

// Fully fused MPM. Lane pairing: t = 2m+half; column a = m%96, row-group
// g = m/96 (0..3). Each lane holds HALF a W column (48 regs) so nothing
// spills at 3 waves/SIMD (budget 170 VGPR). Pair combines its b-half maxes
// with one shfl_xor(.,1).
//   M[j,a] = max_b W[a,b]*X[j,b]  (j ≡ g mod 4, two 48-row halves in LDS)
//   y[i,a] = X[i,a]*ns[i,a] + sum_{j in nbr(i)} M[j,a],  i = g + 4*half + 8k
//   X = y / ||y||  (block-wide deterministic reduction)
__global__ __launch_bounds__(T, 3) void k_fused(const float* __restrict__ A,
                                                const float* __restrict__ vec,
                                                float* __restrict__ out) {
    __shared__ float Xs[N * N];            // 36864 B : X (staging for B, then A)
    __shared__ float Mh[48 * N];           // 18432 B : M for one j-half
    __shared__ unsigned char lst[N * 48];  //  4608 B : neighbor lists (ascending j)
    __shared__ short cnt[N];
    __shared__ short cntlo[N];             // neighbors with j < 48
    __shared__ float degA[N];
    __shared__ float degB[N];
    __shared__ float red[T / 64];

    const int t = threadIdx.x;
    const int half = t & 1;
    const int m = t >> 1;
    const int a = m % N;
    const int g = m / N;                    // 0..3
    const int bbase = 48 * half;
    const float s1 = 1.0f / (1.0f + expf(-1.0f));   // sigmoid(1) = diag of B
    const float s1s1 = s1 * s1;

    // ---- setup phase 0: B -> Xs (staging) ----
#pragma unroll
    for (int k = 0; k < 12; ++k) {
        int e = t + k * T;
        int r = e / N, c = e % N;
        float logit;
        if (r == c) {
            logit = 1.0f;
        } else {
            int i = r < c ? r : c;
            int j = r < c ? c : r;
            int idx = i * 95 - (i * (i - 1)) / 2 + (j - i - 1);
            logit = vec[idx];
        }
        Xs[e] = 1.0f / (1.0f + expf(-logit));
    }
    __syncthreads();

    // half a W column into registers (B symmetric), zero diagonal element
    float Wreg[48];
#pragma unroll
    for (int bb = 0; bb < 48; ++bb)
        Wreg[bb] = Xs[(bbase + bb) * N + a] * s1s1;
    if (a >= bbase && a < bbase + 48) Wreg[a - bbase] = 0.0f;

    // degB: column sums of B (== row sums, symmetric)
    if (t < N) {
        float s = 0.f;
        for (int r = 0; r < N; ++r) s += Xs[r * N + t];
        degB[t] = s;
    }
    __syncthreads();   // all reads of B done

    // ---- setup phase 1: A -> Xs (staging) ----
#pragma unroll
    for (int k = 0; k < 12; ++k) {
        int e = t + k * T;
        Xs[e] = A[e];
    }
    __syncthreads();

    if (t < N) {
        float s = 0.f;
        for (int r = 0; r < N; ++r) s += Xs[r * N + t];   // A symmetric
        degA[t] = s;
    } else if (t < 2 * N) {
        int i = t - N;
        int c_ = 0, clo = 0;
        for (int j = 0; j < N; ++j) {
            if (j == 48) clo = c_;
            if (j != i && Xs[j * N + i] > 0.5f)            // A symmetric
                lst[i * 48 + c_++] = (unsigned char)j;
        }
        cnt[i] = (short)c_;
        cntlo[i] = (short)clo;
    }
    __syncthreads();   // lists/degs ready, Xs(A) reads done

    // node-sim coefficients for this thread's 12 output rows (i = g+4*half+8k)
    float ns_reg[12];
#pragma unroll
    for (int k = 0; k < 12; ++k) {
        int i = g + 4 * half + 8 * k;
        ns_reg[k] = s1 / (fabsf(degA[i] - degB[a]) + 1.0f);
    }

    // X0 = 1/96 everywhere (reference normalizes only after each step)
#pragma unroll
    for (int k = 0; k < 12; ++k) Xs[t + k * T] = (1.0f / 96.0f);
    __syncthreads();

    // ---- main loop ----
    float y[12];
    for (int it = 0; it < ITERS; ++it) {
        // diag term first (same summation order as the exact kernel)
#pragma unroll
        for (int k = 0; k < 12; ++k) {
            int i = g + 4 * half + 8 * k;
            y[k] = Xs[i * N + a] * ns_reg[k];
        }

        for (int h = 0; h < 2; ++h) {
            // M for rows j in [48h, 48h+48) with j ≡ g (mod 4): 12 rows/pair
#pragma unroll
            for (int jj = 0; jj < 12; ++jj) {
                int jl = jj * 4 + g;
                const float* xr = &Xs[(48 * h + jl) * N + bbase];
                float m0 = 0.f, m1 = 0.f, m2 = 0.f, m3 = 0.f;
#pragma unroll
                for (int bb = 0; bb < 48; bb += 8) {
                    float4 x0 = *(const float4*)(xr + bb);       // broadcast
                    float4 x1 = *(const float4*)(xr + bb + 4);   // broadcast
                    // fmaxf(fmaxf(m,p),p) -> v_max3_f32
                    m0 = fmaxf(fmaxf(m0, Wreg[bb + 0] * x0.x), Wreg[bb + 1] * x0.y);
                    m1 = fmaxf(fmaxf(m1, Wreg[bb + 2] * x0.z), Wreg[bb + 3] * x0.w);
                    m2 = fmaxf(fmaxf(m2, Wreg[bb + 4] * x1.x), Wreg[bb + 5] * x1.y);
                    m3 = fmaxf(fmaxf(m3, Wreg[bb + 6] * x1.z), Wreg[bb + 7] * x1.w);
                }
                float pm = fmaxf(fmaxf(m0, m1), fmaxf(m2, m3));
                pm = fmaxf(pm, __shfl_xor(pm, 1, 64));   // combine b-halves
                if (half == 0) Mh[jl * N + a] = pm;
            }
            __syncthreads();   // Mh ready

            // aggregate this half's neighbors (ascending j order preserved)
#pragma unroll
            for (int k = 0; k < 12; ++k) {
                int i = g + 4 * half + 8 * k;
                int q0 = h ? (int)cntlo[i] : 0;
                int q1 = h ? (int)cnt[i] : (int)cntlo[i];
                float acc = y[k];
                for (int q = q0; q < q1; ++q) {
                    int j = (int)lst[i * 48 + q];
                    acc += Mh[(j - 48 * h) * N + a];
                }
                y[k] = acc;
            }
            if (h == 0) __syncthreads();   // protect Mh before h=1 rewrite
        }

        // block-wide norm of y (deterministic: fixed tree, fixed order)
        float ss = 0.f;
#pragma unroll
        for (int k = 0; k < 12; ++k) ss = fmaf(y[k], y[k], ss);
#pragma unroll
        for (int mm = 1; mm < 64; mm <<= 1) ss += __shfl_xor(ss, mm, 64);
        if ((t & 63) == 0) red[t >> 6] = ss;
        __syncthreads();                   // red ready (also: agg h=1 reads done)
        float s = 0.f;
#pragma unroll
        for (int w = 0; w < T / 64; ++w) s += red[w];
        float inv = 1.0f / sqrtf(s);
#pragma unroll
        for (int k = 0; k < 12; ++k) {
            int i = g + 4 * half + 8 * k;
            Xs[i * N + a] = y[k] * inv;
        }
        __syncthreads();                   // X ready for next iter
    }

    // ---- output ----
#pragma unroll
    for (int k = 0; k < 12; ++k) {
        int e = t + k * T;
        out[e] = Xs[e];
    }
}

extern "C" void kernel_launch(void* const* d_in, const int* in_sizes, int n_in,
                              void* d_out, int out_size, void* d_ws, size_t ws_size,
                              hipStream_t stream) {
    const float* A = (const float*)d_in[0];     // A_gt, 96*96
    const float* vec = (const float*)d_in[1];   // vec_logits, 4560
    float* out = (float*)d_out;
    k_fused<<<1, T, 0, stream>>>(A, vec, out);
}

// Round 4
// 739.951 us; speedup vs baseline: 6.8967x; 6.8967x over previous
//
#include <hip/hip_runtime.h>
#include <math.h>

#define N 96
#define PAD 100        // padded LDS row stride (floats): breaks 96%32==0 bank alignment
#define T 768          // 12 waves, one workgroup, one CU
#define ITERS 50

// Fully fused MPM, one workgroup.
// Thread map: t = (p<<2)|q ; q = b-quarter (0..3), ap = p%48 = column pair,
// g = p/48 = row group (0..3). Thread owns columns a0=2ap, a0+1 and holds
// W[a0..a0+1][24q..24q+23] in 48 VGPRs.
//   M[j,a] = max_b W[a,b]*X[j,b]: per row j (j%4==g), each quad lane computes
//   the max over its 24-b quarter for both columns, combined via shfl_xor 1,2.
//   y[i,a] accumulation rows: i = g + 4q + 16k (k=0..5), ascending-j neighbor
//   sum (identical order to the bit-exact round-2 kernel).
__global__ __launch_bounds__(T, 1) void k_fused(const float* __restrict__ A,
                                                const float* __restrict__ vec,
                                                float* __restrict__ out) {
    __shared__ float Xs[N * PAD];          // 38400 B : X (staging for B, then A)
    __shared__ float Mh[48 * PAD];         // 19200 B : M for one 48-row half
    __shared__ unsigned char lst[N * 48];  //  4608 B : neighbor lists (ascending j)
    __shared__ short cnt[N];
    __shared__ short cntlo[N];             // neighbors with j < 48
    __shared__ float degA[N];
    __shared__ float degB[N];
    __shared__ float red[T / 64];

    const int t = threadIdx.x;
    const int q = t & 3;                   // b-quarter
    const int p = t >> 2;
    const int ap = p % 48;                 // column-pair id
    const int g = p / 48;                  // row group 0..3
    const int a0 = 2 * ap;
    const float s1 = 1.0f / (1.0f + expf(-1.0f));   // sigmoid(1) = diag of B
    const float s1s1 = s1 * s1;

    // ---- setup phase 0: B -> Xs (staging) ----
#pragma unroll
    for (int k = 0; k < 12; ++k) {
        int e = t + k * T;
        int r = e / N, c = e % N;
        float logit;
        if (r == c) {
            logit = 1.0f;
        } else {
            int i = r < c ? r : c;
            int j = r < c ? c : r;
            int idx = i * 95 - (i * (i - 1)) / 2 + (j - i - 1);
            logit = vec[idx];
        }
        Xs[r * PAD + c] = 1.0f / (1.0f + expf(-logit));
    }
    __syncthreads();

    // W quarter-columns into registers (B symmetric: col a == row a), diag=0
    float Wr0[24], Wr1[24];
#pragma unroll
    for (int bb = 0; bb < 24; ++bb) {
        int b = 24 * q + bb;
        float w0 = Xs[b * PAD + a0] * s1s1;
        float w1 = Xs[b * PAD + a0 + 1] * s1s1;
        if (b == a0) w0 = 0.0f;
        if (b == a0 + 1) w1 = 0.0f;
        Wr0[bb] = w0;
        Wr1[bb] = w1;
    }

    // degB: column sums of B (== row sums, symmetric); identical order to r2
    if (t < N) {
        float s = 0.f;
        for (int r = 0; r < N; ++r) s += Xs[r * PAD + t];
        degB[t] = s;
    }
    __syncthreads();   // all reads of B done

    // ---- setup phase 1: A -> Xs (staging) ----
#pragma unroll
    for (int k = 0; k < 12; ++k) {
        int e = t + k * T;
        Xs[(e / N) * PAD + (e % N)] = A[e];
    }
    __syncthreads();

    if (t < N) {
        float s = 0.f;
        for (int r = 0; r < N; ++r) s += Xs[r * PAD + t];   // A symmetric
        degA[t] = s;
    } else if (t < 2 * N) {
        int i = t - N;
        int c_ = 0, clo = 0;
        for (int j = 0; j < N; ++j) {
            if (j == 48) clo = c_;
            if (j != i && Xs[j * PAD + i] > 0.5f)            // A symmetric
                lst[i * 48 + c_++] = (unsigned char)j;
        }
        cnt[i] = (short)c_;
        cntlo[i] = (short)clo;
    }
    __syncthreads();   // lists/degs ready, Xs(A) reads done

    // node-sim coefficients for this thread's 6 rows x 2 cols
    float ns0[6], ns1[6];
#pragma unroll
    for (int k = 0; k < 6; ++k) {
        int i = g + 4 * q + 16 * k;
        ns0[k] = s1 / (fabsf(degA[i] - degB[a0]) + 1.0f);
        ns1[k] = s1 / (fabsf(degA[i] - degB[a0 + 1]) + 1.0f);
    }

    // X0 = 1/96 everywhere (||X0|| = 1 exactly)
#pragma unroll
    for (int k = 0; k < 12; ++k) {
        int e = t + k * T;
        Xs[(e / N) * PAD + (e % N)] = (1.0f / 96.0f);
    }
    __syncthreads();

    // ---- main loop ----
    float y0[6], y1[6];
    for (int it = 0; it < ITERS; ++it) {
        // diag term first (same summation order as the exact kernel)
#pragma unroll
        for (int k = 0; k < 6; ++k) {
            int i = g + 4 * q + 16 * k;
            y0[k] = Xs[i * PAD + a0] * ns0[k];
            y1[k] = Xs[i * PAD + a0 + 1] * ns1[k];
        }

        for (int h = 0; h < 2; ++h) {
            // M for rows j in [48h,48h+48) with j%4==g : 12 rows, all lanes
            // of a wave share the row (g uniform per wave) -> 4-addr multicast
            for (int jj = 0; jj < 12; ++jj) {
                int jl = g + 4 * jj;                 // 0..47
                const float* xr = &Xs[(48 * h + jl) * PAD + 24 * q];
                float m0 = 0.f, m1 = 0.f;
#pragma unroll
                for (int c = 0; c < 6; ++c) {
                    float4 x = *(const float4*)(xr + 4 * c);
                    // fmaxf(fmaxf(m,p),p) -> v_max3_f32
                    m0 = fmaxf(fmaxf(m0, Wr0[4 * c + 0] * x.x), Wr0[4 * c + 1] * x.y);
                    m0 = fmaxf(fmaxf(m0, Wr0[4 * c + 2] * x.z), Wr0[4 * c + 3] * x.w);
                    m1 = fmaxf(fmaxf(m1, Wr1[4 * c + 0] * x.x), Wr1[4 * c + 1] * x.y);
                    m1 = fmaxf(fmaxf(m1, Wr1[4 * c + 2] * x.z), Wr1[4 * c + 3] * x.w);
                }
                // combine b-quarters across the lane quad (exact: max assoc.)
                m0 = fmaxf(m0, __shfl_xor(m0, 1, 64));
                m0 = fmaxf(m0, __shfl_xor(m0, 2, 64));
                m1 = fmaxf(m1, __shfl_xor(m1, 1, 64));
                m1 = fmaxf(m1, __shfl_xor(m1, 2, 64));
                if (q == 0)
                    *(float2*)&Mh[jl * PAD + a0] = make_float2(m0, m1);
            }
            __syncthreads();   // Mh ready

            // aggregate this half's neighbors (ascending j, same order as r2)
#pragma unroll
            for (int k = 0; k < 6; ++k) {
                int i = g + 4 * q + 16 * k;
                int q0 = h ? (int)cntlo[i] : 0;
                int q1 = h ? (int)cnt[i] : (int)cntlo[i];
                float acc0 = y0[k], acc1 = y1[k];
                for (int qq = q0; qq < q1; ++qq) {
                    int jl = (int)lst[i * 48 + qq] - 48 * h;
                    float2 mm = *(const float2*)&Mh[jl * PAD + a0];
                    acc0 += mm.x;
                    acc1 += mm.y;
                }
                y0[k] = acc0;
                y1[k] = acc1;
            }
            if (h == 0) __syncthreads();   // protect Mh before h=1 rewrite
        }

        // block-wide norm of y (deterministic fixed tree)
        float ss = 0.f;
#pragma unroll
        for (int k = 0; k < 6; ++k) {
            ss = fmaf(y0[k], y0[k], ss);
            ss = fmaf(y1[k], y1[k], ss);
        }
#pragma unroll
        for (int mm = 1; mm < 64; mm <<= 1) ss += __shfl_xor(ss, mm, 64);
        if ((t & 63) == 0) red[t >> 6] = ss;
        __syncthreads();                   // red ready; h=1 Mh reads done
        float s = 0.f;
#pragma unroll
        for (int w = 0; w < T / 64; ++w) s += red[w];
        float inv = 1.0f / sqrtf(s);
#pragma unroll
        for (int k = 0; k < 6; ++k) {
            int i = g + 4 * q + 16 * k;
            *(float2*)&Xs[i * PAD + a0] = make_float2(y0[k] * inv, y1[k] * inv);
        }
        __syncthreads();                   // X ready for next iter
    }

    // ---- output ----
#pragma unroll
    for (int k = 0; k < 12; ++k) {
        int e = t + k * T;
        out[e] = Xs[(e / N) * PAD + (e % N)];
    }
}

extern "C" void kernel_launch(void* const* d_in, const int* in_sizes, int n_in,
                              void* d_out, int out_size, void* d_ws, size_t ws_size,
                              hipStream_t stream) {
    const float* A = (const float*)d_in[0];     // A_gt, 96*96
    const float* vec = (const float*)d_in[1];   // vec_logits, 4560
    float* out = (float*)d_out;
    k_fused<<<1, T, 0, stream>>>(A, vec, out);
}